// Round 2
// baseline (127.523 us; speedup 1.0000x reference)
//
#include <hip/hip_runtime.h>
#include <math.h>

#define LN10_SQ 5.3018981104783984f   // (ln 10)^2
#define LOG2_10 3.3219280948873623f

constexpr int NWIN = 30;              // N (window length) — fixed by problem
constexpr int SEGS_PER_BLOCK = 64;
constexpr int NF = SEGS_PER_BLOCK + NWIN - 1;   // 93 frames per block
constexpr int TSPLIT = 4;             // t-range splits (one wave each)

// sid: 0 Lx, 1 Rx, 2 Ly, 3 Ry, 4 rxr, 5 rxi, 6 ryr, 7 ryi
__global__ __launch_bounds__(256, 4) void ec_fused_kernel(
    const float* __restrict__ xlr, const float* __restrict__ xli,
    const float* __restrict__ xrre, const float* __restrict__ xrim,
    const float* __restrict__ ylr, const float* __restrict__ yli,
    const float* __restrict__ yrre, const float* __restrict__ yrim,
    const float* __restrict__ cf, const float* __restrict__ taus,
    const float* __restrict__ gammas, const float* __restrict__ sigeps,
    const float* __restrict__ sigdel, const int* __restrict__ fids,
    float* __restrict__ out, int F, int S, int T, int G, int K)
{
    __shared__ float4 ttabA[128];     // cos(wt), sin(wt), cos(2wt), sin(2wt)
    __shared__ float2 ttabB[128];     // 2*Dt, 2*Dt^2 (= 2*deltexp)
    __shared__ float4 gtab[64];       // g2p*ee, g2m*ee, gp*Eg, gm*Eg
    __shared__ float  sser[8][96];    // per-frame band series (row stride 96)
    __shared__ float  red[256];

    const int tid = threadIdx.x;
    const int band = blockIdx.y;
    const int seg_base = blockIdx.x * SEGS_PER_BLOCK;
    const float cw = cf[band];

    // ---- band row range from fids (robust to int32 or int64 storage) ----
    int lo, hi;
    if (fids[1] == 0) {               // int64 little-endian layout
        lo = fids[4 * band] - 1;
        hi = fids[4 * band + 2];
    } else {                          // int32 layout
        lo = fids[2 * band] - 1;
        hi = fids[2 * band + 1];
    }
    lo = lo < 0 ? 0 : lo;
    hi = hi > K ? K : hi;

    // ---- tables (threads not used for staging) ----
    {
        int gg = tid - 100;
        if (gg >= 0 && gg < G) {
            float gam = gammas[gg];
            float se = sigeps[gg];
            float ee = expf(2.0f * LN10_SQ * se * se);
            float Eg = expf(0.5f * LN10_SQ * se * se);
            float g2p = exp2f(2.0f * gam * LOG2_10);
            float g2m = exp2f(-2.0f * gam * LOG2_10);
            float gp = exp2f(gam * LOG2_10);
            float gm = exp2f(-gam * LOG2_10);
            gtab[gg] = make_float4(g2p * ee, g2m * ee, gp * Eg, gm * Eg);
        }
        int tt = tid - 156;
        if (tt >= 0 && tt < T) {
            float tau = taus[tt];
            float wt = cw * tau;
            float sn1, cs1, sn2, cs2;
            sincosf(wt, &sn1, &cs1);
            sincosf(2.0f * wt, &sn2, &cs2);
            float sd = sigdel[tt];
            float Dt = expf(-0.5f * cw * cw * sd * sd);
            ttabA[tt] = make_float4(cs1, sn1, cs2, sn2);
            ttabB[tt] = make_float2(2.0f * Dt, 2.0f * Dt * Dt);
        }
    }

    // ---- stage per-frame band series directly from inputs ----
    for (int j = tid; j < NF; j += 256) {
        int f = seg_base + j;
        float Lx = 0.f, Rx = 0.f, Ly = 0.f, Ry = 0.f;
        float rxr = 0.f, rxi = 0.f, ryr = 0.f, ryi = 0.f;
        if (f < F) {
            for (int k = lo; k < hi; ++k) {
                int idx = k * F + f;
                float a = xlr[idx], b = xli[idx], c = xrre[idx], d = xrim[idx];
                Lx = fmaf(a, a, fmaf(b, b, Lx));
                Rx = fmaf(c, c, fmaf(d, d, Rx));
                rxr = fmaf(c, a, fmaf(d, b, rxr));     // Re(conj(xr)*xl)
                rxi = fmaf(c, b, rxi) - d * a;         // Im(conj(xr)*xl)
                float e = ylr[idx], g = yli[idx], h = yrre[idx], i2 = yrim[idx];
                Ly = fmaf(e, e, fmaf(g, g, Ly));
                Ry = fmaf(h, h, fmaf(i2, i2, Ry));
                ryr = fmaf(h, e, fmaf(i2, g, ryr));
                ryi = fmaf(h, g, ryi) - i2 * e;
            }
        }
        sser[0][j] = Lx;  sser[1][j] = Rx;
        sser[2][j] = Ly;  sser[3][j] = Ry;
        sser[4][j] = rxr; sser[5][j] = rxi;
        sser[6][j] = ryr; sser[7][j] = ryi;
    }
    __syncthreads();

    const int segL = tid & (SEGS_PER_BLOCK - 1);
    const int split = tid >> 6;

    // ---- 8 window sums + 36 windowed products over NWIN frames ----
    float s0=0,s1=0,s2=0,s3=0,s4=0,s5=0,s6=0,s7=0;
    float c00=0,c01=0,c02=0,c03=0,c04=0,c05=0,c06=0,c07=0;
    float c11=0,c12=0,c13=0,c14=0,c15=0,c16=0,c17=0;
    float c22=0,c23=0,c24=0,c25=0,c26=0,c27=0;
    float c33=0,c34=0,c35=0,c36=0,c37=0;
    float c44=0,c45=0,c46=0,c47=0;
    float c55=0,c56=0,c57=0;
    float c66=0,c67=0;
    float c77=0;
    #pragma unroll 5
    for (int n = 0; n < NWIN; ++n) {
        float v0 = sser[0][segL + n], v1 = sser[1][segL + n];
        float v2 = sser[2][segL + n], v3 = sser[3][segL + n];
        float v4 = sser[4][segL + n], v5 = sser[5][segL + n];
        float v6 = sser[6][segL + n], v7 = sser[7][segL + n];
        s0+=v0; s1+=v1; s2+=v2; s3+=v3; s4+=v4; s5+=v5; s6+=v6; s7+=v7;
        c00=fmaf(v0,v0,c00); c01=fmaf(v0,v1,c01); c02=fmaf(v0,v2,c02); c03=fmaf(v0,v3,c03);
        c04=fmaf(v0,v4,c04); c05=fmaf(v0,v5,c05); c06=fmaf(v0,v6,c06); c07=fmaf(v0,v7,c07);
        c11=fmaf(v1,v1,c11); c12=fmaf(v1,v2,c12); c13=fmaf(v1,v3,c13); c14=fmaf(v1,v4,c14);
        c15=fmaf(v1,v5,c15); c16=fmaf(v1,v6,c16); c17=fmaf(v1,v7,c17);
        c22=fmaf(v2,v2,c22); c23=fmaf(v2,v3,c23); c24=fmaf(v2,v4,c24); c25=fmaf(v2,v5,c25);
        c26=fmaf(v2,v6,c26); c27=fmaf(v2,v7,c27);
        c33=fmaf(v3,v3,c33); c34=fmaf(v3,v4,c34); c35=fmaf(v3,v5,c35); c36=fmaf(v3,v6,c36);
        c37=fmaf(v3,v7,c37);
        c44=fmaf(v4,v4,c44); c45=fmaf(v4,v5,c45); c46=fmaf(v4,v6,c46); c47=fmaf(v4,v7,c47);
        c55=fmaf(v5,v5,c55); c56=fmaf(v5,v6,c56); c57=fmaf(v5,v7,c57);
        c66=fmaf(v6,v6,c66); c67=fmaf(v6,v7,c67);
        c77=fmaf(v7,v7,c77);
    }

    // centered: C(u,v) = Σuv − Σu·Σv/N
    const float rN = 1.0f / (float)NWIN;
    #define CEN(a,b) fmaf(-(s##a * rN), s##b, c##a##b)

    float t46 = CEN(4,6), t57 = CEN(5,7), t56 = CEN(5,6), t47 = CEN(4,7);
    // pair xy: L1=Lx(0) L2=Ly(2) R1=Rx(1) R2=Ry(3) rho1=rhoy(6,7) rho2=rhox(4,5)
    float A_xy = CEN(0,2), B_xy = CEN(1,3);
    float base_xy = CEN(0,3) + CEN(1,2) + 2.0f * (t46 + t57);
    float sc_xy = CEN(0,6) + CEN(2,4), ss_xy = CEN(0,7) + CEN(2,5);
    float tc_xy = CEN(1,6) + CEN(3,4), ts_xy = CEN(1,7) + CEN(3,5);
    float qr_xy = t46 - t57, qi_xy = t56 + t47;
    // pair xx
    float t44 = CEN(4,4), t55 = CEN(5,5);
    float A_xx = CEN(0,0), B_xx = CEN(1,1);
    float base_xx = 2.0f * CEN(0,1) + 2.0f * (t44 + t55);
    float sc_xx = 2.0f * CEN(0,4), ss_xx = 2.0f * CEN(0,5);
    float tc_xx = 2.0f * CEN(1,4), ts_xx = 2.0f * CEN(1,5);
    float qr_xx = t44 - t55, qi_xx = 2.0f * CEN(4,5);
    // pair yy
    float t66 = CEN(6,6), t77 = CEN(7,7);
    float A_yy = CEN(2,2), B_yy = CEN(3,3);
    float base_yy = 2.0f * CEN(2,3) + 2.0f * (t66 + t77);
    float sc_yy = 2.0f * CEN(2,6), ss_yy = 2.0f * CEN(2,7);
    float tc_yy = 2.0f * CEN(3,6), ts_yy = 2.0f * CEN(3,7);
    float qr_yy = t66 - t77, qi_yy = 2.0f * CEN(6,7);
    #undef CEN

    // ---- sweep (tau, gamma) grid on this wave's t-range ----
    const int tlen = (T + TSPLIT - 1) / TSPLIT;
    const int tstart = split * tlen;
    const int tend = (tstart + tlen < T) ? (tstart + tlen) : T;
    float m = -3.4e38f;
    for (int t = tstart; t < tend; ++t) {
        float4 ta = ttabA[t];
        float2 tb = ttabB[t];
        float w_xy = fmaf(tb.y, fmaf(qi_xy, ta.w, qr_xy * ta.z), base_xy);
        float ud_xy = fmaf(ss_xy, ta.y, sc_xy * ta.x) * tb.x;
        float vd_xy = fmaf(ts_xy, ta.y, tc_xy * ta.x) * tb.x;
        float w_xx = fmaf(tb.y, fmaf(qi_xx, ta.w, qr_xx * ta.z), base_xx);
        float ud_xx = fmaf(ss_xx, ta.y, sc_xx * ta.x) * tb.x;
        float vd_xx = fmaf(ts_xx, ta.y, tc_xx * ta.x) * tb.x;
        float w_yy = fmaf(tb.y, fmaf(qi_yy, ta.w, qr_yy * ta.z), base_yy);
        float ud_yy = fmaf(ss_yy, ta.y, sc_yy * ta.x) * tb.x;
        float vd_yy = fmaf(ts_yy, ta.y, tc_yy * ta.x) * tb.x;
        #pragma unroll 4
        for (int g = 0; g < G; ++g) {
            float4 gt = gtab[g];
            float exy = fmaf(A_xy, gt.x, w_xy);
            exy = fmaf(B_xy, gt.y, exy);
            exy = fmaf(-ud_xy, gt.z, exy);
            exy = fmaf(-vd_xy, gt.w, exy);
            float exx = fmaf(A_xx, gt.x, w_xx);
            exx = fmaf(B_xx, gt.y, exx);
            exx = fmaf(-ud_xx, gt.z, exx);
            exx = fmaf(-vd_xx, gt.w, exx);
            float eyy = fmaf(A_yy, gt.x, w_yy);
            eyy = fmaf(B_yy, gt.y, eyy);
            eyy = fmaf(-ud_yy, gt.z, eyy);
            eyy = fmaf(-vd_yy, gt.w, eyy);
            float den = fmaxf(exx * eyy, 1e-10f);
            float p = exy * __builtin_amdgcn_rsqf(den);
            m = fmaxf(m, p);
        }
    }

    // ---- reduce max across the 4 t-splits ----
    red[tid] = m;
    __syncthreads();
    if (tid < SEGS_PER_BLOCK) {
        float r = fmaxf(fmaxf(red[tid], red[tid + 64]),
                        fmaxf(red[tid + 128], red[tid + 192]));
        int seg = seg_base + tid;
        if (seg < S) out[(size_t)band * S + seg] = r;
    }
}

// ---------------- host launch -----------------------------------------
extern "C" void kernel_launch(void* const* d_in, const int* in_sizes, int n_in,
                              void* d_out, int out_size, void* d_ws, size_t ws_size,
                              hipStream_t stream) {
    const float* xlr  = (const float*)d_in[0];
    const float* xli  = (const float*)d_in[1];
    const float* xrre = (const float*)d_in[2];
    const float* xrim = (const float*)d_in[3];
    const float* ylr  = (const float*)d_in[4];
    const float* yli  = (const float*)d_in[5];
    const float* yrre = (const float*)d_in[6];
    const float* yrim = (const float*)d_in[7];
    const float* cfp  = (const float*)d_in[8];
    const float* taus = (const float*)d_in[9];
    const float* gammas = (const float*)d_in[10];
    const float* sigeps = (const float*)d_in[11];
    const float* sigdel = (const float*)d_in[12];
    const int*   fids = (const int*)d_in[13];

    const int J = in_sizes[8];
    const int T = in_sizes[9];
    const int G = in_sizes[10];
    const int S = out_size / J;          // segments
    const int F = S + NWIN - 1;          // frames
    const int K = in_sizes[0] / F;       // spectral rows

    dim3 b(256), g((S + SEGS_PER_BLOCK - 1) / SEGS_PER_BLOCK, J);
    ec_fused_kernel<<<g, b, 0, stream>>>(xlr, xli, xrre, xrim,
                                         ylr, yli, yrre, yrim,
                                         cfp, taus, gammas, sigeps, sigdel,
                                         fids, (float*)d_out, F, S, T, G, K);
}

// Round 3
// 126.251 us; speedup vs baseline: 1.0101x; 1.0101x over previous
//
#include <hip/hip_runtime.h>
#include <math.h>

#define LN10_SQ 5.3018981104783984f   // (ln 10)^2
#define LOG2_10 3.3219280948873623f

constexpr int NWIN = 30;              // N (window length) — fixed by problem
constexpr int SEGS_PER_BLOCK = 64;
constexpr int NFRM = SEGS_PER_BLOCK + NWIN - 1;   // 93 frames per block
constexpr int NTHREADS = 512;         // 8 waves
constexpr int TSPLIT = 8;             // one wave per t-chunk

// sid: 0 Lx, 1 Rx, 2 Ly, 3 Ry, 4 rxr, 5 rxi, 6 ryr, 7 ryi
__global__ __launch_bounds__(NTHREADS, 8) void ec_fused_kernel(
    const float* __restrict__ xlr, const float* __restrict__ xli,
    const float* __restrict__ xrre, const float* __restrict__ xrim,
    const float* __restrict__ ylr, const float* __restrict__ yli,
    const float* __restrict__ yrre, const float* __restrict__ yrim,
    const float* __restrict__ cf, const float* __restrict__ taus,
    const float* __restrict__ gammas, const float* __restrict__ sigeps,
    const float* __restrict__ sigdel, const int* __restrict__ fids,
    float* __restrict__ out, int F, int S, int T, int G, int K)
{
    __shared__ float4 ttabA[128];     // cos(wt), sin(wt), cos(2wt), sin(2wt)
    __shared__ float2 ttabB[128];     // 2*Dt, 2*Dt^2 (= 2*deltexp)
    __shared__ float4 gtab[64];       // g2p*ee, g2m*ee, gp*Eg, gm*Eg
    __shared__ float  sser[8][96];    // per-frame band series
    __shared__ float  scal[27][64];   // 27 derived scalars per segment
    __shared__ float  red[NTHREADS];

    const int tid = threadIdx.x;
    const int band = blockIdx.y;
    const int seg_base = blockIdx.x * SEGS_PER_BLOCK;
    const float cw = cf[band];

    // ---- band row range from fids (robust to int32 or int64 storage) ----
    int lo, hi;
    if (fids[1] == 0) {               // int64 little-endian layout
        lo = fids[4 * band] - 1;
        hi = fids[4 * band + 2];
    } else {                          // int32 layout
        lo = fids[2 * band] - 1;
        hi = fids[2 * band + 1];
    }
    lo = lo < 0 ? 0 : lo;
    hi = hi > K ? K : hi;

    // ---- tables: threads disjoint from the staging range ----
    {
        int tt = tid - 128;
        if (tt >= 0 && tt < T) {
            float tau = taus[tt];
            float wt = cw * tau;
            float sn1, cs1, sn2, cs2;
            sincosf(wt, &sn1, &cs1);
            sincosf(2.0f * wt, &sn2, &cs2);
            float sd = sigdel[tt];
            float Dt = expf(-0.5f * cw * cw * sd * sd);
            ttabA[tt] = make_float4(cs1, sn1, cs2, sn2);
            ttabB[tt] = make_float2(2.0f * Dt, 2.0f * Dt * Dt);
        }
        int gg = tid - 256;
        if (gg >= 0 && gg < G) {
            float gam = gammas[gg];
            float se = sigeps[gg];
            float ee = expf(2.0f * LN10_SQ * se * se);
            float Eg = expf(0.5f * LN10_SQ * se * se);
            float g2p = exp2f(2.0f * gam * LOG2_10);
            float g2m = exp2f(-2.0f * gam * LOG2_10);
            float gp = exp2f(gam * LOG2_10);
            float gm = exp2f(-gam * LOG2_10);
            gtab[gg] = make_float4(g2p * ee, g2m * ee, gp * Eg, gm * Eg);
        }
    }

    // ---- stage per-frame band series directly from inputs ----
    if (tid < NFRM) {
        int j = tid;
        int f = seg_base + j;
        float Lx = 0.f, Rx = 0.f, Ly = 0.f, Ry = 0.f;
        float rxr = 0.f, rxi = 0.f, ryr = 0.f, ryi = 0.f;
        if (f < F) {
            for (int k = lo; k < hi; ++k) {
                int idx = k * F + f;
                float a = xlr[idx], b = xli[idx], c = xrre[idx], d = xrim[idx];
                Lx = fmaf(a, a, fmaf(b, b, Lx));
                Rx = fmaf(c, c, fmaf(d, d, Rx));
                rxr = fmaf(c, a, fmaf(d, b, rxr));     // Re(conj(xr)*xl)
                rxi = fmaf(c, b, rxi) - d * a;         // Im(conj(xr)*xl)
                float e = ylr[idx], g = yli[idx], h = yrre[idx], i2 = yrim[idx];
                Ly = fmaf(e, e, fmaf(g, g, Ly));
                Ry = fmaf(h, h, fmaf(i2, i2, Ry));
                ryr = fmaf(h, e, fmaf(i2, g, ryr));
                ryi = fmaf(h, g, ryi) - i2 * e;
            }
        }
        sser[0][j] = Lx;  sser[1][j] = Rx;
        sser[2][j] = Ly;  sser[3][j] = Ry;
        sser[4][j] = rxr; sser[5][j] = rxi;
        sser[6][j] = ryr; sser[7][j] = ryi;
    }
    __syncthreads();

    // ---- one wave computes the 27 derived scalars per segment ----
    if (tid < SEGS_PER_BLOCK) {
        const int segL = tid;
        float s0=0,s1=0,s2=0,s3=0,s4=0,s5=0,s6=0,s7=0;
        float c00=0,c01=0,c02=0,c03=0,c04=0,c05=0,c06=0,c07=0;
        float c11=0,c12=0,c13=0,c14=0,c15=0,c16=0,c17=0;
        float c22=0,c23=0,c24=0,c25=0,c26=0,c27=0;
        float c33=0,c34=0,c35=0,c36=0,c37=0;
        float c44=0,c45=0,c46=0,c47=0;
        float c55=0,c56=0,c57=0;
        float c66=0,c67=0;
        float c77=0;
        #pragma unroll 5
        for (int n = 0; n < NWIN; ++n) {
            float v0 = sser[0][segL + n], v1 = sser[1][segL + n];
            float v2 = sser[2][segL + n], v3 = sser[3][segL + n];
            float v4 = sser[4][segL + n], v5 = sser[5][segL + n];
            float v6 = sser[6][segL + n], v7 = sser[7][segL + n];
            s0+=v0; s1+=v1; s2+=v2; s3+=v3; s4+=v4; s5+=v5; s6+=v6; s7+=v7;
            c00=fmaf(v0,v0,c00); c01=fmaf(v0,v1,c01); c02=fmaf(v0,v2,c02); c03=fmaf(v0,v3,c03);
            c04=fmaf(v0,v4,c04); c05=fmaf(v0,v5,c05); c06=fmaf(v0,v6,c06); c07=fmaf(v0,v7,c07);
            c11=fmaf(v1,v1,c11); c12=fmaf(v1,v2,c12); c13=fmaf(v1,v3,c13); c14=fmaf(v1,v4,c14);
            c15=fmaf(v1,v5,c15); c16=fmaf(v1,v6,c16); c17=fmaf(v1,v7,c17);
            c22=fmaf(v2,v2,c22); c23=fmaf(v2,v3,c23); c24=fmaf(v2,v4,c24); c25=fmaf(v2,v5,c25);
            c26=fmaf(v2,v6,c26); c27=fmaf(v2,v7,c27);
            c33=fmaf(v3,v3,c33); c34=fmaf(v3,v4,c34); c35=fmaf(v3,v5,c35); c36=fmaf(v3,v6,c36);
            c37=fmaf(v3,v7,c37);
            c44=fmaf(v4,v4,c44); c45=fmaf(v4,v5,c45); c46=fmaf(v4,v6,c46); c47=fmaf(v4,v7,c47);
            c55=fmaf(v5,v5,c55); c56=fmaf(v5,v6,c56); c57=fmaf(v5,v7,c57);
            c66=fmaf(v6,v6,c66); c67=fmaf(v6,v7,c67);
            c77=fmaf(v7,v7,c77);
        }
        const float rN = 1.0f / (float)NWIN;
        #define CEN(a,b) fmaf(-(s##a * rN), s##b, c##a##b)
        float t46 = CEN(4,6), t57 = CEN(5,7), t56 = CEN(5,6), t47 = CEN(4,7);
        // pair xy
        scal[0][segL] = CEN(0,2);                              // A
        scal[1][segL] = CEN(1,3);                              // B
        scal[2][segL] = CEN(0,3) + CEN(1,2) + 2.0f*(t46+t57);  // base
        scal[3][segL] = CEN(0,6) + CEN(2,4);                   // sc
        scal[4][segL] = CEN(0,7) + CEN(2,5);                   // ss
        scal[5][segL] = CEN(1,6) + CEN(3,4);                   // tc
        scal[6][segL] = CEN(1,7) + CEN(3,5);                   // ts
        scal[7][segL] = t46 - t57;                             // qr
        scal[8][segL] = t56 + t47;                             // qi
        // pair xx
        float t44 = CEN(4,4), t55 = CEN(5,5);
        scal[9][segL]  = CEN(0,0);
        scal[10][segL] = CEN(1,1);
        scal[11][segL] = 2.0f*CEN(0,1) + 2.0f*(t44+t55);
        scal[12][segL] = 2.0f*CEN(0,4);
        scal[13][segL] = 2.0f*CEN(0,5);
        scal[14][segL] = 2.0f*CEN(1,4);
        scal[15][segL] = 2.0f*CEN(1,5);
        scal[16][segL] = t44 - t55;
        scal[17][segL] = 2.0f*CEN(4,5);
        // pair yy
        float t66 = CEN(6,6), t77 = CEN(7,7);
        scal[18][segL] = CEN(2,2);
        scal[19][segL] = CEN(3,3);
        scal[20][segL] = 2.0f*CEN(2,3) + 2.0f*(t66+t77);
        scal[21][segL] = 2.0f*CEN(2,6);
        scal[22][segL] = 2.0f*CEN(2,7);
        scal[23][segL] = 2.0f*CEN(3,6);
        scal[24][segL] = 2.0f*CEN(3,7);
        scal[25][segL] = t66 - t77;
        scal[26][segL] = 2.0f*CEN(6,7);
        #undef CEN
    }
    __syncthreads();

    // ---- every thread: read its segment's scalars, sweep its t-chunk ----
    const int seg = tid & (SEGS_PER_BLOCK - 1);
    const int split = tid >> 6;                    // wave-uniform
    const float A_xy = scal[0][seg],  B_xy = scal[1][seg],  base_xy = scal[2][seg];
    const float sc_xy = scal[3][seg], ss_xy = scal[4][seg];
    const float tc_xy = scal[5][seg], ts_xy = scal[6][seg];
    const float qr_xy = scal[7][seg], qi_xy = scal[8][seg];
    const float A_xx = scal[9][seg],  B_xx = scal[10][seg], base_xx = scal[11][seg];
    const float sc_xx = scal[12][seg], ss_xx = scal[13][seg];
    const float tc_xx = scal[14][seg], ts_xx = scal[15][seg];
    const float qr_xx = scal[16][seg], qi_xx = scal[17][seg];
    const float A_yy = scal[18][seg], B_yy = scal[19][seg], base_yy = scal[20][seg];
    const float sc_yy = scal[21][seg], ss_yy = scal[22][seg];
    const float tc_yy = scal[23][seg], ts_yy = scal[24][seg];
    const float qr_yy = scal[25][seg], qi_yy = scal[26][seg];

    const int tstart = __builtin_amdgcn_readfirstlane((split * T) / TSPLIT);
    const int tend   = __builtin_amdgcn_readfirstlane(((split + 1) * T) / TSPLIT);

    float m = -3.4e38f;
    for (int t = tstart; t < tend; ++t) {
        float4 ta = ttabA[t];
        float2 tb = ttabB[t];
        float w_xy = fmaf(tb.y, fmaf(qi_xy, ta.w, qr_xy * ta.z), base_xy);
        float ud_xy = fmaf(ss_xy, ta.y, sc_xy * ta.x) * tb.x;
        float vd_xy = fmaf(ts_xy, ta.y, tc_xy * ta.x) * tb.x;
        float w_xx = fmaf(tb.y, fmaf(qi_xx, ta.w, qr_xx * ta.z), base_xx);
        float ud_xx = fmaf(ss_xx, ta.y, sc_xx * ta.x) * tb.x;
        float vd_xx = fmaf(ts_xx, ta.y, tc_xx * ta.x) * tb.x;
        float w_yy = fmaf(tb.y, fmaf(qi_yy, ta.w, qr_yy * ta.z), base_yy);
        float ud_yy = fmaf(ss_yy, ta.y, sc_yy * ta.x) * tb.x;
        float vd_yy = fmaf(ts_yy, ta.y, tc_yy * ta.x) * tb.x;
        #pragma unroll 4
        for (int g = 0; g < G; ++g) {
            float4 gt = gtab[g];
            float exy = fmaf(A_xy, gt.x, w_xy);
            exy = fmaf(B_xy, gt.y, exy);
            exy = fmaf(-ud_xy, gt.z, exy);
            exy = fmaf(-vd_xy, gt.w, exy);
            float exx = fmaf(A_xx, gt.x, w_xx);
            exx = fmaf(B_xx, gt.y, exx);
            exx = fmaf(-ud_xx, gt.z, exx);
            exx = fmaf(-vd_xx, gt.w, exx);
            float eyy = fmaf(A_yy, gt.x, w_yy);
            eyy = fmaf(B_yy, gt.y, eyy);
            eyy = fmaf(-ud_yy, gt.z, eyy);
            eyy = fmaf(-vd_yy, gt.w, eyy);
            float den = fmaxf(exx * eyy, 1e-10f);
            float p = exy * __builtin_amdgcn_rsqf(den);
            m = fmaxf(m, p);
        }
    }

    // ---- reduce max across the 8 t-splits ----
    red[tid] = m;
    __syncthreads();
    if (tid < SEGS_PER_BLOCK) {
        float r = red[tid];
        #pragma unroll
        for (int kk = 1; kk < TSPLIT; ++kk)
            r = fmaxf(r, red[tid + 64 * kk]);
        int sg = seg_base + tid;
        if (sg < S) out[(size_t)band * S + sg] = r;
    }
}

// ---------------- host launch -----------------------------------------
extern "C" void kernel_launch(void* const* d_in, const int* in_sizes, int n_in,
                              void* d_out, int out_size, void* d_ws, size_t ws_size,
                              hipStream_t stream) {
    const float* xlr  = (const float*)d_in[0];
    const float* xli  = (const float*)d_in[1];
    const float* xrre = (const float*)d_in[2];
    const float* xrim = (const float*)d_in[3];
    const float* ylr  = (const float*)d_in[4];
    const float* yli  = (const float*)d_in[5];
    const float* yrre = (const float*)d_in[6];
    const float* yrim = (const float*)d_in[7];
    const float* cfp  = (const float*)d_in[8];
    const float* taus = (const float*)d_in[9];
    const float* gammas = (const float*)d_in[10];
    const float* sigeps = (const float*)d_in[11];
    const float* sigdel = (const float*)d_in[12];
    const int*   fids = (const int*)d_in[13];

    const int J = in_sizes[8];
    const int T = in_sizes[9];
    const int G = in_sizes[10];
    const int S = out_size / J;          // segments
    const int F = S + NWIN - 1;          // frames
    const int K = in_sizes[0] / F;       // spectral rows

    dim3 b(NTHREADS), g((S + SEGS_PER_BLOCK - 1) / SEGS_PER_BLOCK, J);
    ec_fused_kernel<<<g, b, 0, stream>>>(xlr, xli, xrre, xrim,
                                         ylr, yli, yrre, yrim,
                                         cfp, taus, gammas, sigeps, sigdel,
                                         fids, (float*)d_out, F, S, T, G, K);
}